// Round 3
// baseline (157.981 us; speedup 1.0000x reference)
//
#include <hip/hip_runtime.h>

typedef __attribute__((ext_vector_type(4))) float f32x4;
typedef __attribute__((ext_vector_type(8))) short s16x8;

#define C_DIM 256
#define H_DIM 128
#define W_DIM 512
#define HW    (H_DIM * W_DIM)      /* 65536  */
#define CHW   (C_DIM * HW)         /* 16777216 */
#define WS_NEED (2ull * 128 * 512 * 256 * 2)   /* 67108864 B: bf16 [b,h,n,k] */

__device__ __forceinline__ unsigned short f2bf(float f) {
    unsigned u = __builtin_bit_cast(unsigned, f);
    u = (u + 0x7FFFu + ((u >> 16) & 1u)) >> 16;   // round-to-nearest-even
    return (unsigned short)u;
}

// ---------------- K1: transpose+convert img2 -> ws bf16 [b,h][n=512][k=256] ----
// Tile 64c x 64w per WG (256 thr). Read f32 coalesced, LDS staging, write bf16 coalesced.
__global__ __launch_bounds__(256) void transpose_kernel(
    const float* __restrict__ img2, unsigned short* __restrict__ bws)
{
    __shared__ unsigned short tile[64][65];
    const int t = threadIdx.x;
    const int d = blockIdx.x;               // 2*128*8*4 = 8192
    const int cb = d & 3, wb = (d >> 2) & 7, bh = d >> 5;
    const float* src = img2 + (size_t)bh * W_DIM + (size_t)(cb * 64) * HW + wb * 64;

    // read: c = t>>2 (0..63), 16 w per thread
    {
        const int c = t >> 2, w0 = (t & 3) << 4;
        const float* p = src + (size_t)c * HW + w0;
        #pragma unroll
        for (int i = 0; i < 16; i += 4) {
            f32x4 v = *(const f32x4*)(p + i);
            #pragma unroll
            for (int j = 0; j < 4; ++j) tile[c][w0 + i + j] = f2bf(v[j]);
        }
    }
    __syncthreads();

    // write: n_l = t>>2 (0..63), 16 c per thread -> out[bh][n][k]
    {
        const int n_l = t >> 2, c4 = (t & 3) << 4;
        unsigned short vals[16];
        #pragma unroll
        for (int i = 0; i < 16; ++i) vals[i] = tile[c4 + i][n_l];
        unsigned short* dst = bws + ((size_t)bh * 512 + wb * 64 + n_l) * 256 + cb * 64 + c4;
        *(s16x8*)(dst)     = *(s16x8*)&vals[0];
        *(s16x8*)(dst + 8) = *(s16x8*)&vals[8];
    }
}

// ---------------- K2: fused costvolume. A: f32->bf16 LDS (once). B: direct bf16 frags from ws.
__global__ __launch_bounds__(512, 4) void costvol_kernel(
    const float* __restrict__ img1, const unsigned short* __restrict__ bws,
    const float* __restrict__ intri1,
    const float* __restrict__ extri1, const float* __restrict__ extri2,
    float* __restrict__ out)
{
    __shared__ __align__(16) unsigned char smem[32768];
    unsigned short* Alds = (unsigned short*)smem;  // [64][256] bf16, [m][k], 16B-block XOR swizzle

    const int t = threadIdx.x;
    const int d = blockIdx.x;
    // XCD swizzle: the 8 blocks sharing (b,h) get dispatch ids stride-8 apart -> same XCD
    const int win = d >> 6, pos = d & 63;
    const int bh    = win * 8 + (pos & 7);
    const int w1blk = pos >> 3;
    const int b = bh >> 7, h = bh & 127;
    const int w1base = w1blk * 64;

    const float* i1 = img1 + (size_t)b * CHW + (size_t)h * W_DIM;

    // ---- stage A once: rows w1base..+63, all K=256, transposed to [m][k] bf16
    {
        const int c    = t >> 1;                 // 0..255
        const int wseg = (t & 1) << 5;           // 0 or 32
        const float* src = i1 + (size_t)c * HW + (size_t)(w1base + wseg);
        #pragma unroll
        for (int i0 = 0; i0 < 32; i0 += 4) {
            f32x4 v = *(const f32x4*)(src + i0);
            #pragma unroll
            for (int j = 0; j < 4; ++j) {
                const int w = wseg + i0 + j;
                Alds[w * 256 + ((((c >> 3) ^ (w & 15)) << 3) | (c & 7))] = f2bf(v[j]);
            }
        }
    }
    __syncthreads();

    const int wn = t >> 6, lane = t & 63;
    const int lrow = lane & 15, hq = lane >> 4;

    // B fragment pointers into ws: lane covers col n, k = 32*kc + 8*hq + j (16B contiguous)
    const unsigned short* pb[4];
    #pragma unroll
    for (int ct = 0; ct < 4; ++ct)
        pb[ct] = bws + ((size_t)bh * 512 + 64 * wn + 16 * ct + lrow) * 256 + 8 * hq;

    f32x4 acc[4][4] = {};

    #pragma unroll
    for (int kc = 0; kc < 8; ++kc) {
        s16x8 afr[4];
        #pragma unroll
        for (int rt = 0; rt < 4; ++rt) {
            const int row = 16 * rt + lrow;
            const int kb  = (kc << 2) + hq;
            afr[rt] = *(const s16x8*)&Alds[row * 256 + ((kb ^ (row & 15)) << 3)];
        }
        #pragma unroll
        for (int ct = 0; ct < 4; ++ct) {
            const s16x8 bfr = *(const s16x8*)(pb[ct] + (kc << 5));
            #pragma unroll
            for (int rt = 0; rt < 4; ++rt)
                acc[rt][ct] = __builtin_amdgcn_mfma_f32_16x16x32_bf16(afr[rt], bfr, acc[rt][ct], 0, 0, 0);
        }
    }

    __syncthreads();   // A LDS dead; reuse for cross-wave reduction

    // ---- epilogue: per-row Se = sum(e), Sei = sum(e*col | col<=w1), Me = max(e | col<=w1)
    // D layout (m89): col = lane&15, row = 4*(lane>>4) + reg
    float (*red)[64][3] = (float(*)[64][3])smem;
    #pragma unroll
    for (int rt = 0; rt < 4; ++rt) {
        #pragma unroll
        for (int r = 0; r < 4; ++r) {
            const int row = 16 * rt + 4 * hq + r;
            const int w1g = w1base + row;
            float Se = 0.f, Sei = 0.f, Me = 0.f;
            #pragma unroll
            for (int ct = 0; ct < 4; ++ct) {
                const int col = 64 * wn + 16 * ct + lrow;
                const float e = __expf(acc[rt][ct][r] * 0.0625f);   // fold 1/sqrt(256)
                Se += e;
                if (col <= w1g) { Sei += e * (float)col; Me = fmaxf(Me, e); }
            }
            #pragma unroll
            for (int m = 1; m < 16; m <<= 1) {
                Se  += __shfl_xor(Se,  m, 64);
                Sei += __shfl_xor(Sei, m, 64);
                Me   = fmaxf(Me, __shfl_xor(Me, m, 64));
            }
            if (lrow == 0) {
                red[wn][row][0] = Se;
                red[wn][row][1] = Sei;
                red[wn][row][2] = Me;
            }
        }
    }
    __syncthreads();

    if (t < 64) {
        const int row = t;
        float Se = 0.f, Sei = 0.f, Me = 0.f;
        #pragma unroll
        for (int q = 0; q < 8; ++q) {
            Se  += red[q][row][0];
            Sei += red[q][row][1];
            Me   = fmaxf(Me, red[q][row][2]);
        }
        const int w1g = w1base + row;
        const float corresp = Sei / Se;            // soft-argmax (masked numerator, full denominator)
        const float conf    = Me / Se;             // max of post-softmax masked prob
        float disp = fabsf(corresp - (float)w1g) * (1.0f / 512.0f);
        disp = fmaxf(disp, 0.1f);
        const float fx = intri1[b * 9];
        const float dx = extri1[b * 16 + 3]  - extri2[b * 16 + 3];
        const float dy = extri1[b * 16 + 7]  - extri2[b * 16 + 7];
        const float dz = extri1[b * 16 + 11] - extri2[b * 16 + 11];
        const float bl = sqrtf(dx * dx + dy * dy + dz * dz);
        const float depth = fx * bl / disp;
        const int oidx = b * HW + h * W_DIM + w1g;
        out[oidx]          = depth;
        out[2 * HW + oidx] = conf;                 // confidence block starts at B*H*W = 131072
    }
}

// ---------------- Fallback (R2 kernel): direct f32 B loads, used only if ws too small
__global__ __launch_bounds__(512, 4) void costvol_fallback(
    const float* __restrict__ img1, const float* __restrict__ img2,
    const float* __restrict__ intri1,
    const float* __restrict__ extri1, const float* __restrict__ extri2,
    float* __restrict__ out)
{
    __shared__ __align__(16) unsigned char smem[32768];
    unsigned short* Alds = (unsigned short*)smem;
    const int t = threadIdx.x;
    const int d = blockIdx.x;
    const int win = d >> 6, pos = d & 63;
    const int bh    = win * 8 + (pos & 7);
    const int w1blk = pos >> 3;
    const int b = bh >> 7, h = bh & 127;
    const int w1base = w1blk * 64;
    const float* i1 = img1 + (size_t)b * CHW + (size_t)h * W_DIM;
    const float* i2 = img2 + (size_t)b * CHW + (size_t)h * W_DIM;
    {
        const int c    = t >> 1;
        const int wseg = (t & 1) << 5;
        const float* src = i1 + (size_t)c * HW + (size_t)(w1base + wseg);
        #pragma unroll
        for (int i0 = 0; i0 < 32; i0 += 4) {
            f32x4 v = *(const f32x4*)(src + i0);
            #pragma unroll
            for (int j = 0; j < 4; ++j) {
                const int w = wseg + i0 + j;
                Alds[w * 256 + ((((c >> 3) ^ (w & 15)) << 3) | (c & 7))] = f2bf(v[j]);
            }
        }
    }
    __syncthreads();
    const int wn = t >> 6, lane = t & 63;
    const int lrow = lane & 15, hq = lane >> 4;
    const float* pb[4];
    #pragma unroll
    for (int ct = 0; ct < 4; ++ct)
        pb[ct] = i2 + (size_t)(8 * hq) * HW + (64 * wn + 16 * ct + lrow);
    f32x4 acc[4][4] = {};
    for (int kc = 0; kc < 8; ++kc) {
        s16x8 afr[4];
        #pragma unroll
        for (int rt = 0; rt < 4; ++rt) {
            const int row = 16 * rt + lrow;
            const int kb  = (kc << 2) + hq;
            afr[rt] = *(const s16x8*)&Alds[row * 256 + ((kb ^ (row & 15)) << 3)];
        }
        #pragma unroll
        for (int ct = 0; ct < 4; ++ct) {
            const float* p = pb[ct] + (size_t)(32 * kc) * HW;
            float f[8];
            #pragma unroll
            for (int j = 0; j < 8; ++j) f[j] = p[(size_t)j * HW];
            s16x8 bfr;
            #pragma unroll
            for (int j = 0; j < 8; ++j) bfr[j] = (short)f2bf(f[j]);
            #pragma unroll
            for (int rt = 0; rt < 4; ++rt)
                acc[rt][ct] = __builtin_amdgcn_mfma_f32_16x16x32_bf16(afr[rt], bfr, acc[rt][ct], 0, 0, 0);
        }
    }
    __syncthreads();
    float (*red)[64][3] = (float(*)[64][3])smem;
    #pragma unroll
    for (int rt = 0; rt < 4; ++rt) {
        #pragma unroll
        for (int r = 0; r < 4; ++r) {
            const int row = 16 * rt + 4 * hq + r;
            const int w1g = w1base + row;
            float Se = 0.f, Sei = 0.f, Me = 0.f;
            #pragma unroll
            for (int ct = 0; ct < 4; ++ct) {
                const int col = 64 * wn + 16 * ct + lrow;
                const float e = __expf(acc[rt][ct][r] * 0.0625f);
                Se += e;
                if (col <= w1g) { Sei += e * (float)col; Me = fmaxf(Me, e); }
            }
            #pragma unroll
            for (int m = 1; m < 16; m <<= 1) {
                Se  += __shfl_xor(Se,  m, 64);
                Sei += __shfl_xor(Sei, m, 64);
                Me   = fmaxf(Me, __shfl_xor(Me, m, 64));
            }
            if (lrow == 0) { red[wn][row][0] = Se; red[wn][row][1] = Sei; red[wn][row][2] = Me; }
        }
    }
    __syncthreads();
    if (t < 64) {
        const int row = t;
        float Se = 0.f, Sei = 0.f, Me = 0.f;
        #pragma unroll
        for (int q = 0; q < 8; ++q) {
            Se += red[q][row][0]; Sei += red[q][row][1]; Me = fmaxf(Me, red[q][row][2]);
        }
        const int w1g = w1base + row;
        const float corresp = Sei / Se;
        const float conf    = Me / Se;
        float disp = fabsf(corresp - (float)w1g) * (1.0f / 512.0f);
        disp = fmaxf(disp, 0.1f);
        const float fx = intri1[b * 9];
        const float dx = extri1[b * 16 + 3]  - extri2[b * 16 + 3];
        const float dy = extri1[b * 16 + 7]  - extri2[b * 16 + 7];
        const float dz = extri1[b * 16 + 11] - extri2[b * 16 + 11];
        const float bl = sqrtf(dx * dx + dy * dy + dz * dz);
        const int oidx = b * HW + h * W_DIM + w1g;
        out[oidx]          = fx * bl / disp;
        out[2 * HW + oidx] = conf;
    }
}

extern "C" void kernel_launch(void* const* d_in, const int* in_sizes, int n_in,
                              void* d_out, int out_size, void* d_ws, size_t ws_size,
                              hipStream_t stream) {
    const float* img1   = (const float*)d_in[0];
    const float* img2   = (const float*)d_in[1];
    const float* intri1 = (const float*)d_in[2];
    const float* extri1 = (const float*)d_in[4];
    const float* extri2 = (const float*)d_in[5];
    if (ws_size >= WS_NEED) {
        unsigned short* bws = (unsigned short*)d_ws;
        transpose_kernel<<<dim3(8192), dim3(256), 0, stream>>>(img2, bws);
        costvol_kernel<<<dim3(2048), dim3(512), 0, stream>>>(
            img1, bws, intri1, extri1, extri2, (float*)d_out);
    } else {
        costvol_fallback<<<dim3(2048), dim3(512), 0, stream>>>(
            img1, img2, intri1, extri1, extri2, (float*)d_out);
    }
}